// Round 5
// baseline (711.552 us; speedup 1.0000x reference)
//
#include <hip/hip_runtime.h>

// IIR2DResidual: separable bidirectional first-order IIR (a = 0.5, mirror border)
// along W then H on (N=4, H=512, W=512, C=64) fp32 channels-last, then
// out = x + sigmoid(alpha[c]) * (y - x).
//
// R6: LDS-staged scans. R0-R5 all plateaued at ~3.1 TB/s because the compiler
// serializes the register-window loads (MLP=1/wave: 48 x ~900cy dependent HBM
// accesses; VGPR_Count 76-100 << 96-float window across all variants). Fix by
// construction: stage the window via __builtin_amdgcn_global_load_lds width=16
// (no VGPR destination -> nothing for the allocator to serialize; 10-12 KiB
// in flight per wave), then run the serial scan against LDS (~6-12cy/read,
// compiler fine-grained lgkmcnt) instead of HBM.
//
// Chunking (unchanged math): T=32 outputs, K=8 warm-up halo (0.5^8 ~ 4e-3;
// prev absmax 1.6e-2 vs threshold 6.6e-2). Valid-only staging: positions
// outside [0,L) are never read -- forward scan holds carry at the edge
// (exact mirror at w0=0; right edge yf[L-1] fixpoint makes the backward
// init exact: c2 = carry after forward loop covers both cases).
//
// H-pass: wave = one h-line chunk; window contiguous in global (48 x 256 B)
//   -> 10-12 x 1 KiB DMAs; waves independent -> vmcnt(0) only, no barrier.
// V-pass: block = (n, w-quad, chunk); stages [pos][4w][64ch] tile (1 KiB per
//   position, contiguous); one __syncthreads; wave scans one w column.
// LDS 48 KB/block -> 3 blocks/CU, 12 waves/CU; VGPR ~40.
//
// ws robustness: group images to fit ws; if ws can't hold one image, fall back
// to H-pass into out + in-place V-pass (no scratch).

constexpr int Tc   = 32;            // output chunk per wave
constexpr int Kc   = 8;             // warm-up halo
constexpr int WIN  = Tc + 2 * Kc;   // 48 positions max per window
constexpr int L    = 512;
constexpr int C    = 64;
constexpr int W    = 512;
constexpr int H    = 512;
constexpr int CHUNKS = L / Tc;      // 16

typedef float f2 __attribute__((ext_vector_type(2)));

// Async global->LDS DMA, 16 B/lane (1 KiB per wave-instruction).
// Global source is per-lane (g + lane*4 floats); LDS dest is wave-uniform
// base, HW adds lane*16 B. Tracked by vmcnt.
__device__ __forceinline__ void dma16(const float* g, float* l) {
    __builtin_amdgcn_global_load_lds(
        (const __attribute__((address_space(1))) unsigned int*)g,
        (__attribute__((address_space(3))) unsigned int*)l,
        16, 0, 0);
}

// ---------------- H-pass: scan along w, one wave per (n,h,chunk) ----------------
__global__ __launch_bounds__(256)
void iir_h(const float* __restrict__ in, float* __restrict__ out)
{
    __shared__ float lds[4][WIN * 64];          // 4 waves x 48 pos x 64 ch = 48 KB

    // XCD-aware bijective swizzle (gridDim.x % 8 == 0 always)
    const int nb8 = (int)gridDim.x >> 3;
    const int bid = (int)blockIdx.x;
    const int lb  = (bid & 7) * nb8 + (bid >> 3);

    const int wv   = threadIdx.x >> 6;
    const int lane = threadIdx.x & 63;
    const int chunk = lb & (CHUNKS - 1);
    const int hq    = (lb >> 4) & 127;          // h quad
    const int n     = lb >> 11;                 // 2048 blocks per image
    const int h     = hq * 4 + wv;
    const int w0    = chunk * Tc;

    const int v0  = max(0, w0 - Kc);            // first staged position
    const int v1  = min(L, w0 + Tc + Kc);       // one past last staged position
    const int cnt = v1 - v0;                    // 40 or 48 (always %4 == 0)
    const int nkb = cnt >> 2;                   // 1-KiB DMAs (4 positions each)

    const float* lbase = in + ((size_t)(n * H + h)) * W * C + v0 * C;
    float* Wl = &lds[wv][0];

    // --- stage window: 10-12 async 1-KiB DMAs, all in flight ---
    for (int i = 0; i < nkb; ++i)
        dma16(lbase + i * 256 + lane * 4, Wl + i * 256);
    asm volatile("s_waitcnt vmcnt(0)" ::: "memory");
    __builtin_amdgcn_sched_barrier(0);

    // --- forward scan in LDS (in place): yf = 0.5*x + 0.5*carry ---
    float carry = Wl[lane];                     // x[v0] (mirror-exact at w0=0)
    for (int s = 0; s < cnt; ++s) {
        const float x = Wl[s * 64 + lane];
        carry = 0.5f * x + 0.5f * carry;
        Wl[s * 64 + lane] = carry;
    }

    // --- backward scan + store outputs [w0, w0+Tc) ---
    float c2 = carry;                           // yf[last valid] (right-edge exact)
    const int sOutLo = w0 - v0;                 // first output slot
    float* obase = out + ((size_t)(n * H + h)) * W * C;
    for (int s = cnt - 1; s >= sOutLo; --s) {
        const float yf = Wl[s * 64 + lane];
        c2 = 0.5f * yf + 0.5f * c2;
        const int p = v0 + s;
        if (p < w0 + Tc)                        // wave-uniform
            obase[p * C + lane] = c2;
    }
}

// ---------------- V-pass: scan along h, block = (n, w-quad, chunk) ----------------
__global__ __launch_bounds__(256)
void iir_v(const float* __restrict__ in, float* __restrict__ out,
           const float* __restrict__ xres, const float* __restrict__ alpha)
{
    __shared__ float lds[WIN * 256];            // 48 pos x (4 w x 64 ch) = 48 KB

    const int nb8 = (int)gridDim.x >> 3;
    const int bid = (int)blockIdx.x;
    const int lb  = (bid & 7) * nb8 + (bid >> 3);

    const int wv   = threadIdx.x >> 6;          // w sub-line within quad
    const int lane = threadIdx.x & 63;          // channel
    const int chunk = lb & (CHUNKS - 1);
    const int wg    = (lb >> 4) & 127;          // w quad group
    const int n     = lb >> 11;
    const int w0    = chunk * Tc;

    const int v0  = max(0, w0 - Kc);
    const int v1  = min(L, w0 + Tc + Kc);
    const int cnt = v1 - v0;                    // 40 or 48

    const float* nbase = in + (size_t)n * H * W * C;

    // --- stage tile: position i = contiguous 1 KiB (4 w x 64 ch) at h=v0+i ---
    for (int i = wv; i < cnt; i += 4)
        dma16(nbase + (size_t)(v0 + i) * W * C + wg * 256 + lane * 4,
              &lds[i * 256]);
    asm volatile("s_waitcnt vmcnt(0)" ::: "memory");
    __syncthreads();

    // --- forward scan in LDS: wave wv owns column w = wg*4 + wv ---
    float* Wl = &lds[wv * 64];
    float carry = Wl[lane];
    for (int s = 0; s < cnt; ++s) {
        const float x = Wl[s * 256 + lane];
        carry = 0.5f * x + 0.5f * carry;
        Wl[s * 256 + lane] = carry;
    }

    // --- backward scan + residual combine + store ---
    const float mix = 1.0f / (1.0f + __expf(-alpha[lane]));
    float c2 = carry;
    const int sOutLo = w0 - v0;
    const size_t colbase = (size_t)n * H * W * C + (size_t)(wg * 4 + wv) * C + lane;
    for (int s = cnt - 1; s >= sOutLo; --s) {
        const float yf = Wl[s * 256 + lane];
        c2 = 0.5f * yf + 0.5f * c2;
        const int p = v0 + s;
        if (p < w0 + Tc) {                      // wave-uniform
            const size_t idx = colbase + (size_t)p * W * C;
            const float xv = xres[idx];
            out[idx] = xv + mix * (c2 - xv);
        }
    }
}

// Emergency V-pass when ws can't hold even one image: in-place on y (the
// H-pass result already in d_out). One wave owns 2 (n,w) lines x 32 channel
// pairs -> reads/writes only its own indices, race-free, zero scratch.
__global__ __launch_bounds__(256)
void iir_vpass_inplace(float* __restrict__ y, const float* __restrict__ xres,
                       const float* __restrict__ alpha)
{
    const int lane = threadIdx.x & 63;
    const int sub  = lane >> 5;
    const int c0   = (lane & 31) << 1;
    const int lg   = blockIdx.x * 4 + (threadIdx.x >> 6);  // [0, N*W/2)
    const int n = lg >> 8;
    const int w = ((lg & 255) << 1) + sub;
    const int base   = (n * H * W + w) * C + c0;
    const int stride = W * C;

    f2 carry = *(const f2*)(y + base);          // mirror init
    for (int h = 0; h < H; ++h) {
        const int idx = base + h * stride;
        f2 cur = *(const f2*)(y + idx);
        carry = 0.5f * cur + 0.5f * carry;
        *(f2*)(y + idx) = carry;
    }
    const f2 av = *(const f2*)(alpha + c0);
    f2 mix;
#pragma unroll
    for (int q = 0; q < 2; ++q)
        mix[q] = 1.0f / (1.0f + __expf(-av[q]));
    f2 c2 = *(const f2*)(y + base + (H - 1) * stride);
    for (int h = H - 1; h >= 0; --h) {
        const int idx = base + h * stride;
        f2 cur = *(const f2*)(y + idx);
        c2 = 0.5f * cur + 0.5f * c2;
        const f2 xv = *(const f2*)(xres + idx);
        *(f2*)(y + idx) = xv + mix * (c2 - xv);
    }
}

extern "C" void kernel_launch(void* const* d_in, const int* in_sizes, int n_in,
                              void* d_out, int out_size, void* d_ws, size_t ws_size,
                              hipStream_t stream) {
    const float* x     = (const float*)d_in[0];
    const float* alpha = (const float*)d_in[1];
    float* out = (float*)d_out;
    float* t   = (float*)d_ws;

    const size_t imgElems = (size_t)H * W * C;          // 16,777,216
    const size_t imgBytes = imgElems * sizeof(float);   // 64 MiB
    const int    N        = 4;

    int g = (int)(ws_size / imgBytes);   // images that fit in ws
    if (g > N) g = N;

    if (g >= 1) {
        // Process images in groups of g: H-pass (x->ws), V-pass+combine (ws->out).
        for (int i0 = 0; i0 < N; i0 += g) {
            const int ni = (i0 + g <= N) ? g : (N - i0);
            const size_t off = (size_t)i0 * imgElems;
            // 2048 blocks per image (128 quads x 16 chunks); grid % 8 == 0.
            const dim3 grid((unsigned)(ni * 2048)), block(256);
            iir_h<<<grid, block, 0, stream>>>(x + off, t);
            iir_v<<<grid, block, 0, stream>>>(t, out + off, x + off, alpha);
        }
    } else {
        // No usable scratch: H-pass x -> out, then in-place streaming V-pass.
        const dim3 block(256);
        iir_h<<<dim3(4 * 2048), block, 0, stream>>>(x, out);
        iir_vpass_inplace<<<dim3(256), block, 0, stream>>>(out, x, alpha);
    }
}